// Round 1
// baseline (1184.425 us; speedup 1.0000x reference)
//
#include <hip/hip_runtime.h>
#include <hip/hip_bf16.h>
#include <stdint.h>

typedef unsigned short u16;
typedef unsigned int   u32;
typedef __attribute__((ext_vector_type(4))) float f32x4;
typedef __attribute__((ext_vector_type(2))) float f32x2;
typedef __attribute__((ext_vector_type(8))) short s16x8;

#define DEV __device__ __forceinline__

static constexpr int EDIM  = 1024;
static constexpr int NB    = 48;            // num
static constexpr int KWN   = 48;            // kw_num
static constexpr int BB    = 8;             // batch
static constexpr int MROWS = BB * NB * KWN; // 18432
static constexpr int MT    = MROWS / 128;   // 144 m-tiles

DEV float b2f(u16 x) { u32 u = ((u32)x) << 16; float f; __builtin_memcpy(&f, &u, 4); return f; }
DEV u16 f2b(float f) {
    u32 u; __builtin_memcpy(&u, &f, 4);
    u32 r = (u + 0x7FFFu + ((u >> 16) & 1u)) >> 16;
    return (u16)r;
}

#define GLDS16(gsrc, ldst) __builtin_amdgcn_global_load_lds( \
    (const __attribute__((address_space(1))) u32*)(gsrc),    \
    (__attribute__((address_space(3))) u32*)(ldst), 16, 0, 0)

// ---------------- weight convert+transpose: W[K][N] f32 -> Wt[N][K] bf16 ----
__global__ void wconv_kernel(const float* __restrict__ W, u16* __restrict__ Wt,
                             int K, int N) {
    __shared__ u16 tile[64][65];
    int n0 = blockIdx.x * 64, k0 = blockIdx.y * 64;
    int tx = threadIdx.x & 63, ty = threadIdx.x >> 6;
#pragma unroll
    for (int i = 0; i < 16; ++i) {
        int r = ty * 16 + i;
        tile[r][tx] = f2b(W[(size_t)(k0 + r) * N + n0 + tx]);
    }
    __syncthreads();
#pragma unroll
    for (int i = 0; i < 16; ++i) {
        int r = ty * 16 + i;
        Wt[(size_t)(n0 + r) * K + k0 + tx] = tile[tx][r];
    }
}

// ---------------- gather emb f32 -> Xc bf16 in col-attn layout -------------
// Xc[(b*48+k)*48+n][e] = emb[(n*48+k)*8+b][e]
__global__ void gather_kernel(const float* __restrict__ emb, u16* __restrict__ Xc) {
    int gid = blockIdx.x * 256 + threadIdx.x;   // MROWS*512 total
    int r = gid >> 9, c2 = gid & 511;
    int b = r / 2304, k = (r / 48) % 48, n = r % 48;
    int src = (n * 48 + k) * 8 + b;
    f32x2 v = *(const f32x2*)&emb[(size_t)src * EDIM + c2 * 2];
    u32 p = (u32)f2b(v.x) | ((u32)f2b(v.y) << 16);
    *(u32*)&Xc[(size_t)r * EDIM + c2 * 2] = p;
}

__global__ void zero_kernel(float* __restrict__ p, int n) {
    int i = blockIdx.x * 256 + threadIdx.x;
    if (i < n) p[i] = 0.f;
}

// ---------------- GEMM: C[M][1024] = act(A @ Bt^T + bias) ------------------
// A: [MROWS][1024] bf16 (DUALA: A1 for k<1024, A2 for k>=1024)
// Bt: [1024][KTOT] bf16 (transposed weight)
template<int KTOT, bool DUALA, bool TANH, bool PERM, bool SCORE, bool WRC>
__global__ __launch_bounds__(256, 2) void gemm_kernel(
    const u16* __restrict__ A1, const u16* __restrict__ A2,
    const u16* __restrict__ Bt, const float* __restrict__ bias,
    u16* __restrict__ C, const float* __restrict__ w2, float* __restrict__ score) {
    __shared__ u16 lA[128 * 32];
    __shared__ u16 lB[128 * 32];
    int bid = blockIdx.x;
    int mt = bid % MT, nt = bid / MT;     // 144%8==0 -> A-panel sharers same XCD
    int m0 = mt * 128, n0 = nt * 128;
    int tid = threadIdx.x, lane = tid & 63, wv = tid >> 6;
    int wm = wv >> 1, wn = wv & 1;
    int arow = lane >> 2, acol = (lane & 3) * 8;
    int fr = lane & 15, fk = (lane >> 4) * 8;

    f32x4 acc[4][4];
#pragma unroll
    for (int i = 0; i < 4; ++i)
#pragma unroll
        for (int j = 0; j < 4; ++j) acc[i][j] = (f32x4)0.f;

    for (int kt = 0; kt < KTOT / 32; ++kt) {
        int k0 = kt * 32;
        const u16* As = A1; int ka = k0;
        if (DUALA && k0 >= 1024) { As = A2; ka = k0 - 1024; }
        __syncthreads();
#pragma unroll
        for (int i = 0; i < 2; ++i) {
            int c = wv * 2 + i;
            const u16* ga = As + ((size_t)(m0 + c * 16 + arow) * 1024 + ka + acol);
            GLDS16(ga, &lA[c * 512]);
            const u16* gb = Bt + ((size_t)(n0 + c * 16 + arow) * KTOT + k0 + acol);
            GLDS16(gb, &lB[c * 512]);
        }
        __syncthreads();
        s16x8 af[4], bf[4];
#pragma unroll
        for (int mf = 0; mf < 4; ++mf) af[mf] = *(const s16x8*)&lA[(wm * 64 + mf * 16 + fr) * 32 + fk];
#pragma unroll
        for (int nf = 0; nf < 4; ++nf) bf[nf] = *(const s16x8*)&lB[(wn * 64 + nf * 16 + fr) * 32 + fk];
#pragma unroll
        for (int mf = 0; mf < 4; ++mf)
#pragma unroll
            for (int nf = 0; nf < 4; ++nf)
                acc[mf][nf] = __builtin_amdgcn_mfma_f32_16x16x32_bf16(af[mf], bf[nf], acc[mf][nf], 0, 0, 0);
    }

    int crow4 = (lane >> 4) * 4;
#pragma unroll
    for (int mf = 0; mf < 4; ++mf) {
#pragma unroll
        for (int j = 0; j < 4; ++j) {
            int row = m0 + wm * 64 + mf * 16 + crow4 + j;
            int orow = row;
            if (PERM) {  // (b,k,n) -> (b,n,k)
                int b = row / 2304, k = (row / 48) % 48, n = row % 48;
                orow = (b * 48 + n) * 48 + k;
            }
            float sc_part = 0.f;
#pragma unroll
            for (int nf = 0; nf < 4; ++nf) {
                int col = n0 + wn * 64 + nf * 16 + fr;
                float v = acc[mf][nf][j];
                if (bias) v += bias[col];
                if (TANH) v = tanhf(v);
                if (WRC) C[(size_t)orow * EDIM + col] = f2b(v);
                if (SCORE) sc_part += v * w2[col];
            }
            if (SCORE) {
                sc_part += __shfl_xor(sc_part, 1);
                sc_part += __shfl_xor(sc_part, 2);
                sc_part += __shfl_xor(sc_part, 4);
                sc_part += __shfl_xor(sc_part, 8);
                if (fr == 0) atomicAdd(&score[row], sc_part);
            }
        }
    }
}

// ---------------- attention: 48x48, dh=128, no mask ------------------------
// grid: 384*8 blocks, 64 threads. Q/K/V/O: [384*48][1024] bf16, head h cols h*128..+128
__global__ __launch_bounds__(64) void attn_kernel(
    const u16* __restrict__ Q, const u16* __restrict__ Km,
    const u16* __restrict__ V, u16* __restrict__ O) {
    __shared__ u16 lQ[48 * 136];
    __shared__ u16 lK[48 * 136];
    __shared__ u16 lVt[128 * 72];
    __shared__ u16 lP[48 * 72];
    int bb = blockIdx.x >> 3, h = blockIdx.x & 7;
    int lane = threadIdx.x;
    size_t base = (size_t)bb * 48 * EDIM + h * 128;

#pragma unroll
    for (int i = 0; i < 48; ++i) {
        int li = i * 64 + lane;          // 0..3071
        int row = li >> 6, c2 = li & 63;
        u32 vq = *(const u32*)&Q[base + (size_t)row * EDIM + c2 * 2];
        *(u32*)&lQ[row * 136 + c2 * 2] = vq;
        u32 vk = *(const u32*)&Km[base + (size_t)row * EDIM + c2 * 2];
        *(u32*)&lK[row * 136 + c2 * 2] = vk;
        u32 vv = *(const u32*)&V[base + (size_t)row * EDIM + c2 * 2];
        lVt[(c2 * 2) * 72 + row] = (u16)(vv & 0xffffu);
        lVt[(c2 * 2 + 1) * 72 + row] = (u16)(vv >> 16);
    }
    for (int i = lane; i < 128 * 16; i += 64) { int d = i >> 4, c = 48 + (i & 15); lVt[d * 72 + c] = 0; }
    for (int i = lane; i < 48 * 16; i += 64)  { int t = i >> 4, c = 48 + (i & 15); lP[t * 72 + c] = 0; }
    __syncthreads();

    int fr = lane & 15, fk = (lane >> 4) * 8, crow4 = (lane >> 4) * 4;
    f32x4 sc[3][3];
#pragma unroll
    for (int mf = 0; mf < 3; ++mf)
#pragma unroll
        for (int nf = 0; nf < 3; ++nf) sc[mf][nf] = (f32x4)0.f;

#pragma unroll
    for (int kk = 0; kk < 4; ++kk) {
        s16x8 aq[3], bk[3];
#pragma unroll
        for (int mf = 0; mf < 3; ++mf) aq[mf] = *(const s16x8*)&lQ[(mf * 16 + fr) * 136 + kk * 32 + fk];
#pragma unroll
        for (int nf = 0; nf < 3; ++nf) bk[nf] = *(const s16x8*)&lK[(nf * 16 + fr) * 136 + kk * 32 + fk];
#pragma unroll
        for (int mf = 0; mf < 3; ++mf)
#pragma unroll
            for (int nf = 0; nf < 3; ++nf)
                sc[mf][nf] = __builtin_amdgcn_mfma_f32_16x16x32_bf16(aq[mf], bk[nf], sc[mf][nf], 0, 0, 0);
    }

    const float scale = 0.08838834764831845f;  // 1/sqrt(128)
#pragma unroll
    for (int mf = 0; mf < 3; ++mf) {
#pragma unroll
        for (int j = 0; j < 4; ++j) {
            float v0 = sc[mf][0][j] * scale;
            float v1 = sc[mf][1][j] * scale;
            float v2 = sc[mf][2][j] * scale;
            float mx = fmaxf(v0, fmaxf(v1, v2));
            mx = fmaxf(mx, __shfl_xor(mx, 1));
            mx = fmaxf(mx, __shfl_xor(mx, 2));
            mx = fmaxf(mx, __shfl_xor(mx, 4));
            mx = fmaxf(mx, __shfl_xor(mx, 8));
            float e0 = __expf(v0 - mx), e1 = __expf(v1 - mx), e2 = __expf(v2 - mx);
            float s = e0 + e1 + e2;
            s += __shfl_xor(s, 1);
            s += __shfl_xor(s, 2);
            s += __shfl_xor(s, 4);
            s += __shfl_xor(s, 8);
            float inv = 1.f / s;
            int t = mf * 16 + crow4 + j;
            lP[t * 72 + 0  + fr] = f2b(e0 * inv);
            lP[t * 72 + 16 + fr] = f2b(e1 * inv);
            lP[t * 72 + 32 + fr] = f2b(e2 * inv);
        }
    }
    __syncthreads();

    f32x4 o[3][8];
#pragma unroll
    for (int mf = 0; mf < 3; ++mf)
#pragma unroll
        for (int nf = 0; nf < 8; ++nf) o[mf][nf] = (f32x4)0.f;

#pragma unroll
    for (int kk = 0; kk < 2; ++kk) {
        s16x8 ap[3];
#pragma unroll
        for (int mf = 0; mf < 3; ++mf) ap[mf] = *(const s16x8*)&lP[(mf * 16 + fr) * 72 + kk * 32 + fk];
#pragma unroll
        for (int nf = 0; nf < 8; ++nf) {
            s16x8 bv = *(const s16x8*)&lVt[(nf * 16 + fr) * 72 + kk * 32 + fk];
#pragma unroll
            for (int mf = 0; mf < 3; ++mf)
                o[mf][nf] = __builtin_amdgcn_mfma_f32_16x16x32_bf16(ap[mf], bv, o[mf][nf], 0, 0, 0);
        }
    }
#pragma unroll
    for (int mf = 0; mf < 3; ++mf)
#pragma unroll
        for (int nf = 0; nf < 8; ++nf)
#pragma unroll
            for (int j = 0; j < 4; ++j) {
                int t = mf * 16 + crow4 + j, d = nf * 16 + fr;
                O[base + (size_t)t * EDIM + d] = f2b(o[mf][nf][j]);
            }
}

// ---------------- combine + outputs ----------------------------------------
// o = k*384 + b*48 + n (output layout); r2 = (b*48+n)*48 + k (compute layout)
__global__ void combine_kernel(const u16* __restrict__ RDR, const u16* __restrict__ CDR,
                               const float* __restrict__ srow, const float* __restrict__ scol,
                               const float* __restrict__ emb, float* __restrict__ out) {
    int o = blockIdx.x;
    int k = o / 384, b = (o / 48) & 7, n = o % 48;
    int r2 = (b * 48 + n) * 48 + k;
    float rs = srow[r2], cs = scol[r2];
    float m = fmaxf(rs, cs);
    float e0 = __expf(rs - m), e1 = __expf(cs - m);
    float inv = 1.f / (e0 + e1);
    float w0 = e0 * inv, w1 = e1 * inv;
    const size_t rb = (size_t)r2 * EDIM;
    const size_t ob = (size_t)o * EDIM;
    const size_t eb = ((size_t)(n * 48 + k) * 8 + b) * EDIM;
    float* out_mb  = out + 393216;
    float* out_col = out + 393216 + 18874368;
    float* out_row = out + 393216 + 2 * 18874368;
    for (int e = threadIdx.x; e < EDIM; e += 256) {
        float rv = b2f(RDR[rb + e]);
        float cv = b2f(CDR[rb + e]);
        float hv = emb[eb + e];
        out_mb[ob + e]  = w0 * rv + w1 * cv + hv;
        out_col[ob + e] = cv;
        out_row[ob + e] = rv;
    }
}

// out0[(n*8+b)*1024+e] = mean_k mb[(k*384+b*48+n)*1024+e]
__global__ void mean_kernel(const float* __restrict__ mb, float* __restrict__ out0) {
    int idx = blockIdx.x * 256 + threadIdx.x;  // 393216
    int n = idx >> 13, b = (idx >> 10) & 7, e = idx & 1023;
    float s = 0.f;
#pragma unroll 8
    for (int k = 0; k < 48; ++k) s += mb[((size_t)(k * 384 + b * 48 + n)) * EDIM + e];
    out0[idx] = s * (1.f / 48.f);
}

// ---------------------------------------------------------------------------
extern "C" void kernel_launch(void* const* d_in, const int* in_sizes, int n_in,
                              void* d_out, int out_size, void* d_ws, size_t ws_size,
                              hipStream_t stream) {
    const float* emb    = (const float*)d_in[0];
    const float* Wq_c   = (const float*)d_in[1];
    const float* bq_c   = (const float*)d_in[2];
    const float* Wk_c   = (const float*)d_in[3];
    const float* bk_c   = (const float*)d_in[4];
    const float* Wv_c   = (const float*)d_in[5];
    const float* bv_c   = (const float*)d_in[6];
    const float* Wo_c   = (const float*)d_in[7];
    const float* bo_c   = (const float*)d_in[8];
    const float* Wq_r   = (const float*)d_in[9];
    const float* bq_r   = (const float*)d_in[10];
    const float* Wk_r   = (const float*)d_in[11];
    const float* bk_r   = (const float*)d_in[12];
    const float* Wv_r   = (const float*)d_in[13];
    const float* bv_r   = (const float*)d_in[14];
    const float* Wo_r   = (const float*)d_in[15];
    const float* bo_r   = (const float*)d_in[16];
    const float* W_gen  = (const float*)d_in[17];
    const float* W_mlp1 = (const float*)d_in[18];
    const float* W_mlp2 = (const float*)d_in[19];

    char* ws = (char*)d_ws;
    const size_t WSZ = (size_t)1024 * 1024 * 2;        // 2MB: one ExE bf16
    u16* wt[8];
    for (int i = 0; i < 8; ++i) wt[i] = (u16*)(ws + (size_t)i * WSZ);
    u16* WgT = (u16*)(ws + 8 * WSZ);                   // [1024][2048]
    u16* W1T = (u16*)(ws + 10 * WSZ);                  // [1024][2048]
    size_t off = 12 * WSZ;
    const size_t SZ = (size_t)MROWS * EDIM * 2;        // 37748736
    u16* XA  = (u16*)(ws + off); off += SZ;            // input / attn-out (reused)
    u16* Qb  = (u16*)(ws + off); off += SZ;            // also GEN later
    u16* Kb  = (u16*)(ws + off); off += SZ;
    u16* Vb  = (u16*)(ws + off); off += SZ;
    u16* CDR = (u16*)(ws + off); off += SZ;
    u16* RDR = (u16*)(ws + off); off += SZ;
    float* score_row = (float*)(ws + off); off += (size_t)MROWS * 4;
    float* score_col = (float*)(ws + off); off += (size_t)MROWS * 4;
    (void)ws_size; (void)in_sizes; (void)n_in; (void)out_size;

    dim3 tb(256);
    const float* wsrc[8] = {Wq_c, Wk_c, Wv_c, Wo_c, Wq_r, Wk_r, Wv_r, Wo_r};
    for (int i = 0; i < 8; ++i)
        wconv_kernel<<<dim3(16, 16), tb, 0, stream>>>(wsrc[i], wt[i], 1024, 1024);
    wconv_kernel<<<dim3(16, 32), tb, 0, stream>>>(W_gen, WgT, 2048, 1024);
    wconv_kernel<<<dim3(16, 32), tb, 0, stream>>>(W_mlp1, W1T, 2048, 1024);

    gather_kernel<<<MROWS * 512 / 256, tb, 0, stream>>>(emb, XA);
    zero_kernel<<<(2 * MROWS + 255) / 256, tb, 0, stream>>>(score_row, 2 * MROWS);

    const int GG = MT * 8;  // 1152
    // col QKV
    gemm_kernel<1024, false, false, false, false, true><<<GG, tb, 0, stream>>>(XA, nullptr, wt[0], bq_c, Qb, nullptr, nullptr);
    gemm_kernel<1024, false, false, false, false, true><<<GG, tb, 0, stream>>>(XA, nullptr, wt[1], bk_c, Kb, nullptr, nullptr);
    gemm_kernel<1024, false, false, false, false, true><<<GG, tb, 0, stream>>>(XA, nullptr, wt[2], bv_c, Vb, nullptr, nullptr);
    attn_kernel<<<384 * 8, 64, 0, stream>>>(Qb, Kb, Vb, XA);
    // col out-proj, permuted (b,k,n)->(b,n,k)
    gemm_kernel<1024, false, false, true, false, true><<<GG, tb, 0, stream>>>(XA, nullptr, wt[3], bo_c, CDR, nullptr, nullptr);
    // row QKV
    gemm_kernel<1024, false, false, false, false, true><<<GG, tb, 0, stream>>>(CDR, nullptr, wt[4], bq_r, Qb, nullptr, nullptr);
    gemm_kernel<1024, false, false, false, false, true><<<GG, tb, 0, stream>>>(CDR, nullptr, wt[5], bk_r, Kb, nullptr, nullptr);
    gemm_kernel<1024, false, false, false, false, true><<<GG, tb, 0, stream>>>(CDR, nullptr, wt[6], bv_r, Vb, nullptr, nullptr);
    attn_kernel<<<384 * 8, 64, 0, stream>>>(Qb, Kb, Vb, XA);
    gemm_kernel<1024, false, false, false, false, true><<<GG, tb, 0, stream>>>(XA, nullptr, wt[7], bo_r, RDR, nullptr, nullptr);
    // gen_rep = tanh(concat(RDR,CDR) @ W_gen)   -> Qb (reused as GEN)
    gemm_kernel<2048, true, true, false, false, true><<<GG, tb, 0, stream>>>(RDR, CDR, WgT, nullptr, Qb, nullptr, nullptr);
    // scores (fused tanh + dot W_mlp2)
    gemm_kernel<2048, true, true, false, true, false><<<GG, tb, 0, stream>>>(RDR, Qb, W1T, nullptr, nullptr, W_mlp2, score_row);
    gemm_kernel<2048, true, true, false, true, false><<<GG, tb, 0, stream>>>(CDR, Qb, W1T, nullptr, nullptr, W_mlp2, score_col);

    float* out = (float*)d_out;
    combine_kernel<<<MROWS, tb, 0, stream>>>(RDR, CDR, score_row, score_col, emb, out);
    mean_kernel<<<393216 / 256, tb, 0, stream>>>(out + 393216, out);
}

// Round 2
// 1078.623 us; speedup vs baseline: 1.0981x; 1.0981x over previous
//
#include <hip/hip_runtime.h>
#include <hip/hip_bf16.h>
#include <stdint.h>

typedef unsigned short u16;
typedef unsigned int   u32;
typedef __attribute__((ext_vector_type(4))) float f32x4;
typedef __attribute__((ext_vector_type(2))) float f32x2;
typedef __attribute__((ext_vector_type(8))) short s16x8;

#define DEV __device__ __forceinline__

static constexpr int EDIM  = 1024;
static constexpr int MROWS = 8 * 48 * 48;   // 18432
static constexpr int MT    = MROWS / 128;   // 144 m-tiles

DEV float b2f(u16 x) { u32 u = ((u32)x) << 16; float f; __builtin_memcpy(&f, &u, 4); return f; }
DEV u16 f2b(float f) {
    u32 u; __builtin_memcpy(&u, &f, 4);
    u32 r = (u + 0x7FFFu + ((u >> 16) & 1u)) >> 16;
    return (u16)r;
}

#define GLDS16(gsrc, ldst) __builtin_amdgcn_global_load_lds( \
    (const __attribute__((address_space(1))) u32*)(gsrc),    \
    (__attribute__((address_space(3))) u32*)(ldst), 16, 0, 0)

// ---------------- weight convert+transpose: W[K][N] f32 -> Wt[N][K] bf16 ----
__global__ void wconv_kernel(const float* __restrict__ W, u16* __restrict__ Wt,
                             int K, int N) {
    __shared__ u16 tile[64][65];
    int n0 = blockIdx.x * 64, k0 = blockIdx.y * 64;
    int tx = threadIdx.x & 63, ty = threadIdx.x >> 6;
#pragma unroll
    for (int i = 0; i < 16; ++i) {
        int r = ty * 16 + i;
        tile[r][tx] = f2b(W[(size_t)(k0 + r) * N + n0 + tx]);
    }
    __syncthreads();
#pragma unroll
    for (int i = 0; i < 16; ++i) {
        int r = ty * 16 + i;
        Wt[(size_t)(n0 + r) * K + k0 + tx] = tile[tx][r];
    }
}

__global__ void bconcat_kernel(const float* __restrict__ a, const float* __restrict__ b,
                               const float* __restrict__ c, float* __restrict__ out) {
    int i = blockIdx.x * 256 + threadIdx.x;  // 3072
    out[i] = (i < 1024) ? a[i] : ((i < 2048) ? b[i - 1024] : c[i - 2048]);
}

// ---------------- gather emb f32 -> Xc bf16 in col-attn layout -------------
// Xc[(b*48+k)*48+n][e] = emb[(n*48+k)*8+b][e]
__global__ void gather_kernel(const float* __restrict__ emb, u16* __restrict__ Xc) {
    int gid = blockIdx.x * 256 + threadIdx.x;   // MROWS*512 total
    int r = gid >> 9, c2 = gid & 511;
    int b = r / 2304, k = (r / 48) % 48, n = r % 48;
    int src = (n * 48 + k) * 8 + b;
    f32x2 v = *(const f32x2*)&emb[(size_t)src * EDIM + c2 * 2];
    u32 p = (u32)f2b(v.x) | ((u32)f2b(v.y) << 16);
    *(u32*)&Xc[(size_t)r * EDIM + c2 * 2] = p;
}

__global__ void zero_kernel(float* __restrict__ p, int n) {
    int i = blockIdx.x * 256 + threadIdx.x;
    if (i < n) p[i] = 0.f;
}

// ---------------- GEMM: C[M][ldc] = act(A @ Bt^T + bias) -------------------
// 128x128 tile, BK=32, double-buffered LDS, 2-phase prefetch, swizzled LDS.
// Swizzle: granule (r,q) stored at slot (q + (r>>1))&3 within row r (4x16B).
template<int KTOT, bool DUALA, bool TANH, bool PERM, bool SCORE, bool WRC, int OMAP>
__global__ __launch_bounds__(256, 4) void gemm_kernel(
    const u16* __restrict__ A1, const u16* __restrict__ A2, int lda,
    const u16* __restrict__ Bt, const float* __restrict__ bias,
    u16* __restrict__ C, int ldc, float* __restrict__ outF,
    const float* __restrict__ w2, float* __restrict__ score) {
    __shared__ u16 lA[2][128 * 32];
    __shared__ u16 lB[2][128 * 32];
    int bid = blockIdx.x;
    int mt = bid % MT, nt = bid / MT;     // same-mt blocks land on same XCD (144%8==0)
    int m0 = mt * 128, n0 = nt * 128;
    int tid = threadIdx.x, lane = tid & 63, wv = tid >> 6;
    int wm = wv >> 1, wn = wv & 1;
    int fr = lane & 15, qq = lane >> 4, fk = qq * 8;

    f32x4 acc[4][4];
#pragma unroll
    for (int i = 0; i < 4; ++i)
#pragma unroll
        for (int j = 0; j < 4; ++j) acc[i][j] = (f32x4)0.f;

    // staging lane mapping (swizzled global source, linear LDS dest)
    auto STAGE = [&](int bsel, int kt) {
        int k0 = kt * 32;
        const u16* As = A1; int ka = k0;
        if (DUALA && k0 >= 1024) { As = A2; ka = k0 - 1024; }
#pragma unroll
        for (int i = 0; i < 2; ++i) {
            int c = wv * 2 + i;
            int r = c * 16 + (lane >> 2);
            int qg = ((lane & 3) - (r >> 1)) & 3;
            GLDS16(As + (size_t)(m0 + r) * lda + ka + qg * 8, &lA[bsel][c * 512]);
            GLDS16(Bt + (size_t)(n0 + r) * KTOT + k0 + qg * 8, &lB[bsel][c * 512]);
        }
    };

    constexpr int NT = KTOT / 32;
    STAGE(0, 0);
    for (int kt = 0; kt < NT; ++kt) {
        __syncthreads();                    // drains vmcnt: buf[kt&1] ready
        if (kt + 1 < NT) STAGE((kt + 1) & 1, kt + 1);
        const u16* la = &lA[kt & 1][0];
        const u16* lb = &lB[kt & 1][0];
        s16x8 af[4], bf[4];
#pragma unroll
        for (int mf = 0; mf < 4; ++mf) {
            int rr = wm * 64 + mf * 16 + fr;
            af[mf] = *(const s16x8*)&la[rr * 32 + (((qq + (rr >> 1)) & 3) * 8)];
        }
#pragma unroll
        for (int nf = 0; nf < 4; ++nf) {
            int rn = wn * 64 + nf * 16 + fr;
            bf[nf] = *(const s16x8*)&lb[rn * 32 + (((qq + (rn >> 1)) & 3) * 8)];
        }
#pragma unroll
        for (int mf = 0; mf < 4; ++mf)
#pragma unroll
            for (int nf = 0; nf < 4; ++nf)
                acc[mf][nf] = __builtin_amdgcn_mfma_f32_16x16x32_bf16(af[mf], bf[nf], acc[mf][nf], 0, 0, 0);
    }

    int crow4 = qq * 4;
#pragma unroll
    for (int mf = 0; mf < 4; ++mf) {
#pragma unroll
        for (int j = 0; j < 4; ++j) {
            int row = m0 + wm * 64 + mf * 16 + crow4 + j;
            int orow = row;
            int o32 = 0;
            if (PERM || OMAP == 1) {  // rows are (b,k,n)
                int b = row / 2304, k = (row / 48) % 48, n = row % 48;
                if (PERM) orow = (b * 48 + n) * 48 + k;
                if (OMAP == 1) o32 = k * 384 + b * 48 + n;
            }
            if (OMAP == 2) {          // rows are (b,n,k)
                int b = row / 2304, n = (row / 48) % 48, k = row % 48;
                o32 = k * 384 + b * 48 + n;
            }
            float sc_part = 0.f;
#pragma unroll
            for (int nf = 0; nf < 4; ++nf) {
                int col = n0 + wn * 64 + nf * 16 + fr;
                float v = acc[mf][nf][j];
                if (bias) v += bias[col];
                if (TANH) v = tanhf(v);
                if (WRC) C[(size_t)orow * ldc + col] = f2b(v);
                if (OMAP) outF[(size_t)o32 * EDIM + col] = v;
                if (SCORE) sc_part += v * w2[col];
            }
            if (SCORE) {
                sc_part += __shfl_xor(sc_part, 1);
                sc_part += __shfl_xor(sc_part, 2);
                sc_part += __shfl_xor(sc_part, 4);
                sc_part += __shfl_xor(sc_part, 8);
                if (fr == 0) atomicAdd(&score[row], sc_part);
            }
        }
    }
}

// ---------------- attention: 48x48, dh=128, no mask, in-place O -> Q cols --
// QKV: [MROWS][3072] bf16 (Q cols 0..1023, K 1024.., V 2048..). O written into Q cols.
__global__ __launch_bounds__(64) void attn_kernel(u16* __restrict__ QKV) {
    __shared__ u16 lVt[128 * 72];
    __shared__ u16 lP[48 * 72];
    const int LDQ = 3072;
    int bb = blockIdx.x >> 3, h = blockIdx.x & 7;
    int lane = threadIdx.x;
    u16* Qp = QKV + (size_t)bb * 48 * LDQ + h * 128;
    const u16* Kp = Qp + 1024;
    const u16* Vp = Qp + 2048;

    // stage V transposed: lVt[d][s]
#pragma unroll
    for (int i = 0; i < 48; ++i) {
        u32 vv = *(const u32*)&Vp[(size_t)i * LDQ + lane * 2];
        lVt[(lane * 2) * 72 + i]     = (u16)(vv & 0xffffu);
        lVt[(lane * 2 + 1) * 72 + i] = (u16)(vv >> 16);
    }
    for (int i = lane; i < 128 * 16; i += 64) { int d = i >> 4, c = 48 + (i & 15); lVt[d * 72 + c] = 0; }
    for (int i = lane; i < 48 * 16; i += 64)  { int t = i >> 4, c = 48 + (i & 15); lP[t * 72 + c] = 0; }
    __syncthreads();

    int fr = lane & 15, fk = (lane >> 4) * 8, crow4 = (lane >> 4) * 4;
    f32x4 sc[3][3];
#pragma unroll
    for (int mf = 0; mf < 3; ++mf)
#pragma unroll
        for (int nf = 0; nf < 3; ++nf) sc[mf][nf] = (f32x4)0.f;

#pragma unroll
    for (int kk = 0; kk < 4; ++kk) {
        s16x8 aq[3], bk[3];
#pragma unroll
        for (int mf = 0; mf < 3; ++mf) aq[mf] = *(const s16x8*)&Qp[(size_t)(mf * 16 + fr) * LDQ + kk * 32 + fk];
#pragma unroll
        for (int nf = 0; nf < 3; ++nf) bk[nf] = *(const s16x8*)&Kp[(size_t)(nf * 16 + fr) * LDQ + kk * 32 + fk];
#pragma unroll
        for (int mf = 0; mf < 3; ++mf)
#pragma unroll
            for (int nf = 0; nf < 3; ++nf)
                sc[mf][nf] = __builtin_amdgcn_mfma_f32_16x16x32_bf16(aq[mf], bk[nf], sc[mf][nf], 0, 0, 0);
    }

    const float scale = 0.08838834764831845f;  // 1/sqrt(128)
#pragma unroll
    for (int mf = 0; mf < 3; ++mf) {
#pragma unroll
        for (int j = 0; j < 4; ++j) {
            float v0 = sc[mf][0][j] * scale;
            float v1 = sc[mf][1][j] * scale;
            float v2 = sc[mf][2][j] * scale;
            float mx = fmaxf(v0, fmaxf(v1, v2));
            mx = fmaxf(mx, __shfl_xor(mx, 1));
            mx = fmaxf(mx, __shfl_xor(mx, 2));
            mx = fmaxf(mx, __shfl_xor(mx, 4));
            mx = fmaxf(mx, __shfl_xor(mx, 8));
            float e0 = __expf(v0 - mx), e1 = __expf(v1 - mx), e2 = __expf(v2 - mx);
            float s = e0 + e1 + e2;
            s += __shfl_xor(s, 1);
            s += __shfl_xor(s, 2);
            s += __shfl_xor(s, 4);
            s += __shfl_xor(s, 8);
            float inv = 1.f / s;
            int t = mf * 16 + crow4 + j;
            lP[t * 72 + 0  + fr] = f2b(e0 * inv);
            lP[t * 72 + 16 + fr] = f2b(e1 * inv);
            lP[t * 72 + 32 + fr] = f2b(e2 * inv);
        }
    }
    __syncthreads();

    f32x4 o[3][8];
#pragma unroll
    for (int mf = 0; mf < 3; ++mf)
#pragma unroll
        for (int nf = 0; nf < 8; ++nf) o[mf][nf] = (f32x4)0.f;

#pragma unroll
    for (int kk = 0; kk < 2; ++kk) {
        s16x8 ap[3];
#pragma unroll
        for (int mf = 0; mf < 3; ++mf) ap[mf] = *(const s16x8*)&lP[(mf * 16 + fr) * 72 + kk * 32 + fk];
#pragma unroll
        for (int nf = 0; nf < 8; ++nf) {
            s16x8 bv = *(const s16x8*)&lVt[(nf * 16 + fr) * 72 + kk * 32 + fk];
#pragma unroll
            for (int mf = 0; mf < 3; ++mf)
                o[mf][nf] = __builtin_amdgcn_mfma_f32_16x16x32_bf16(ap[mf], bv, o[mf][nf], 0, 0, 0);
        }
    }
#pragma unroll
    for (int mf = 0; mf < 3; ++mf)
#pragma unroll
        for (int nf = 0; nf < 8; ++nf)
#pragma unroll
            for (int j = 0; j < 4; ++j) {
                int t = mf * 16 + crow4 + j, d = nf * 16 + fr;
                Qp[(size_t)t * LDQ + d] = f2b(o[mf][nf][j]);
            }
}

// ---------------- combine (memory_bank only) --------------------------------
__global__ void combine_kernel(const u16* __restrict__ RDR, const u16* __restrict__ CDR,
                               const float* __restrict__ srow, const float* __restrict__ scol,
                               const float* __restrict__ emb, float* __restrict__ out_mb) {
    int o = blockIdx.x;
    int k = o / 384, b = (o / 48) & 7, n = o % 48;
    int r2 = (b * 48 + n) * 48 + k;
    float rs = srow[r2], cs = scol[r2];
    float m = fmaxf(rs, cs);
    float e0 = __expf(rs - m), e1 = __expf(cs - m);
    float inv = 1.f / (e0 + e1);
    float w0 = e0 * inv, w1 = e1 * inv;
    const size_t rb = (size_t)r2 * EDIM;
    const size_t ob = (size_t)o * EDIM;
    const size_t eb = ((size_t)(n * 48 + k) * 8 + b) * EDIM;
    for (int e = threadIdx.x; e < EDIM; e += 256) {
        float rv = b2f(RDR[rb + e]);
        float cv = b2f(CDR[rb + e]);
        out_mb[ob + e] = w0 * rv + w1 * cv + emb[eb + e];
    }
}

// out0[(n*8+b)*1024+e] = mean_k mb[(k*384+b*48+n)*1024+e]
__global__ void mean_kernel(const float* __restrict__ mb, float* __restrict__ out0) {
    int idx = blockIdx.x * 256 + threadIdx.x;  // 393216
    int n = idx >> 13, b = (idx >> 10) & 7, e = idx & 1023;
    float s = 0.f;
#pragma unroll 8
    for (int k = 0; k < 48; ++k) s += mb[((size_t)(k * 384 + b * 48 + n)) * EDIM + e];
    out0[idx] = s * (1.f / 48.f);
}

// ---------------------------------------------------------------------------
extern "C" void kernel_launch(void* const* d_in, const int* in_sizes, int n_in,
                              void* d_out, int out_size, void* d_ws, size_t ws_size,
                              hipStream_t stream) {
    const float* emb    = (const float*)d_in[0];
    const float* Wq_c   = (const float*)d_in[1];
    const float* bq_c   = (const float*)d_in[2];
    const float* Wk_c   = (const float*)d_in[3];
    const float* bk_c   = (const float*)d_in[4];
    const float* Wv_c   = (const float*)d_in[5];
    const float* bv_c   = (const float*)d_in[6];
    const float* Wo_c   = (const float*)d_in[7];
    const float* bo_c   = (const float*)d_in[8];
    const float* Wq_r   = (const float*)d_in[9];
    const float* bq_r   = (const float*)d_in[10];
    const float* Wk_r   = (const float*)d_in[11];
    const float* bk_r   = (const float*)d_in[12];
    const float* Wv_r   = (const float*)d_in[13];
    const float* bv_r   = (const float*)d_in[14];
    const float* Wo_r   = (const float*)d_in[15];
    const float* bo_r   = (const float*)d_in[16];
    const float* W_gen  = (const float*)d_in[17];
    const float* W_mlp1 = (const float*)d_in[18];
    const float* W_mlp2 = (const float*)d_in[19];

    char* ws = (char*)d_ws;
    size_t off = 0;
    auto alloc = [&](size_t bytes) { char* p = ws + off; off += (bytes + 255) & ~(size_t)255; return p; };
    u16*   WqkvC = (u16*)alloc((size_t)3072 * 1024 * 2);
    u16*   WqkvR = (u16*)alloc((size_t)3072 * 1024 * 2);
    u16*   WoC   = (u16*)alloc((size_t)1024 * 1024 * 2);
    u16*   WoR   = (u16*)alloc((size_t)1024 * 1024 * 2);
    u16*   WgT   = (u16*)alloc((size_t)1024 * 2048 * 2);
    u16*   W1T   = (u16*)alloc((size_t)1024 * 2048 * 2);
    float* bqkvC = (float*)alloc(3072 * 4);
    float* bqkvR = (float*)alloc(3072 * 4);
    u16*   XA    = (u16*)alloc((size_t)MROWS * 1024 * 2);   // gather input; later GEN
    u16*   QKV   = (u16*)alloc((size_t)MROWS * 3072 * 2);   // fused QKV, O in-place
    u16*   CDR   = (u16*)alloc((size_t)MROWS * 1024 * 2);
    u16*   RDR   = (u16*)alloc((size_t)MROWS * 1024 * 2);
    float* score_row = (float*)alloc((size_t)MROWS * 4);
    float* score_col = (float*)alloc((size_t)MROWS * 4);
    (void)ws_size; (void)in_sizes; (void)n_in; (void)out_size;

    dim3 tb(256);
    // weights
    wconv_kernel<<<dim3(16, 16), tb, 0, stream>>>(Wq_c, WqkvC,                   1024, 1024);
    wconv_kernel<<<dim3(16, 16), tb, 0, stream>>>(Wk_c, WqkvC + 1024 * 1024,     1024, 1024);
    wconv_kernel<<<dim3(16, 16), tb, 0, stream>>>(Wv_c, WqkvC + 2 * 1024 * 1024, 1024, 1024);
    wconv_kernel<<<dim3(16, 16), tb, 0, stream>>>(Wo_c, WoC,                     1024, 1024);
    wconv_kernel<<<dim3(16, 16), tb, 0, stream>>>(Wq_r, WqkvR,                   1024, 1024);
    wconv_kernel<<<dim3(16, 16), tb, 0, stream>>>(Wk_r, WqkvR + 1024 * 1024,     1024, 1024);
    wconv_kernel<<<dim3(16, 16), tb, 0, stream>>>(Wv_r, WqkvR + 2 * 1024 * 1024, 1024, 1024);
    wconv_kernel<<<dim3(16, 16), tb, 0, stream>>>(Wo_r, WoR,                     1024, 1024);
    wconv_kernel<<<dim3(16, 32), tb, 0, stream>>>(W_gen,  WgT, 2048, 1024);
    wconv_kernel<<<dim3(16, 32), tb, 0, stream>>>(W_mlp1, W1T, 2048, 1024);
    bconcat_kernel<<<12, tb, 0, stream>>>(bq_c, bk_c, bv_c, bqkvC);
    bconcat_kernel<<<12, tb, 0, stream>>>(bq_r, bk_r, bv_r, bqkvR);

    gather_kernel<<<MROWS * 512 / 256, tb, 0, stream>>>(emb, XA);
    zero_kernel<<<(2 * MROWS + 255) / 256, tb, 0, stream>>>(score_row, 2 * MROWS);

    float* out = (float*)d_out;
    float* out_mb  = out + 393216;
    float* out_col = out + 393216 + 18874368;
    float* out_row = out + 393216 + 2 * 18874368;

    const int G8 = MT * 8, G24 = MT * 24;
    // col QKV (fused, N=3072)
    gemm_kernel<1024, false, false, false, false, true, 0><<<G24, tb, 0, stream>>>(
        XA, nullptr, 1024, WqkvC, bqkvC, QKV, 3072, nullptr, nullptr, nullptr);
    attn_kernel<<<384 * 8, 64, 0, stream>>>(QKV);
    // col out-proj: rows (b,k,n) -> CDR rows (b,n,k); f32 out_col
    gemm_kernel<1024, false, false, true, false, true, 1><<<G8, tb, 0, stream>>>(
        QKV, nullptr, 3072, WoC, bo_c, CDR, 1024, out_col, nullptr, nullptr);
    // row QKV
    gemm_kernel<1024, false, false, false, false, true, 0><<<G24, tb, 0, stream>>>(
        CDR, nullptr, 1024, WqkvR, bqkvR, QKV, 3072, nullptr, nullptr, nullptr);
    attn_kernel<<<384 * 8, 64, 0, stream>>>(QKV);
    // row out-proj: rows (b,n,k) -> RDR; f32 out_row
    gemm_kernel<1024, false, false, false, false, true, 2><<<G8, tb, 0, stream>>>(
        QKV, nullptr, 3072, WoR, bo_r, RDR, 1024, out_row, nullptr, nullptr);
    // gen = tanh(concat(RDR,CDR) @ W_gen) -> XA (reused as GEN)
    gemm_kernel<2048, true, true, false, false, true, 0><<<G8, tb, 0, stream>>>(
        RDR, CDR, 1024, WgT, nullptr, XA, 1024, nullptr, nullptr, nullptr);
    // scores
    gemm_kernel<2048, true, true, false, true, false, 0><<<G8, tb, 0, stream>>>(
        RDR, XA, 1024, W1T, nullptr, nullptr, 1024, nullptr, W_mlp2, score_row);
    gemm_kernel<2048, true, true, false, true, false, 0><<<G8, tb, 0, stream>>>(
        CDR, XA, 1024, W1T, nullptr, nullptr, 1024, nullptr, W_mlp2, score_col);

    combine_kernel<<<MROWS, tb, 0, stream>>>(RDR, CDR, score_row, score_col, emb, out_mb);
    mean_kernel<<<393216 / 256, tb, 0, stream>>>(out_mb, out);
}